// Round 5
// baseline (551.826 us; speedup 1.0000x reference)
//
#include <hip/hip_runtime.h>

typedef unsigned short u16;
typedef __attribute__((ext_vector_type(8))) short short8;   // 8 bf16 (4 VGPRs)
typedef __attribute__((ext_vector_type(4))) float f32x4;

__device__ __forceinline__ float us2f(u16 u) {
    union { unsigned int i; float f; } v; v.i = ((unsigned int)u) << 16; return v.f;
}
__device__ __forceinline__ u16 f2bf(float f) {
    unsigned int x = __float_as_uint(f);
    unsigned int r = x + 0x7fffu + ((x >> 16) & 1u);
    return (u16)(r >> 16);
}

#define CC 96
#define SS 16
#define GG 6
#define BN_INV 0.99999500003749969f  // 1/sqrt(1+1e-5)
#define AGRID 1024                   // attn persistent blocks (4096 waves)

// ---------------- kernel 0: tiny precompute ----------------
// WpwT[g][j] = sum_c Wp2[j][c]*Ww1[c][g]   ; cvec[g] = sum_c bp2[c]*Ww1[c][g] + bw1[g]
__global__ __launch_bounds__(256) void precompute_kernel(
    const float* __restrict__ Wp2, const float* __restrict__ Ww1,
    const float* __restrict__ bp2, const float* __restrict__ bw1,
    float* __restrict__ WpwT, float* __restrict__ cvec)
{
    int t = blockIdx.x * 256 + threadIdx.x;
    if (t < GG * CC) {
        int g = t / CC, j = t % CC;
        float acc = 0.f;
        for (int c = 0; c < CC; ++c)
            acc = fmaf(Wp2[j * CC + c], Ww1[c * GG + g], acc);
        WpwT[g * CC + j] = acc;
    } else if (t < GG * CC + GG) {
        int g = t - GG * CC;
        float acc = bw1[g];
        for (int c = 0; c < CC; ++c)
            acc = fmaf(bp2[c], Ww1[c * GG + g], acc);
        cvec[g] = acc;
    }
}

// ---------------- kernel 0b: feat -> bf16 ----------------
__global__ __launch_bounds__(256) void fcvt_kernel(
    const float* __restrict__ feat, u16* __restrict__ featB, int total4)
{
    int i = blockIdx.x * 256 + threadIdx.x;
    if (i < total4) {
        float4 v = *(const float4*)(feat + (size_t)i * 4);
        ushort4 o;
        o.x = f2bf(v.x); o.y = f2bf(v.y); o.z = f2bf(v.z); o.w = f2bf(v.w);
        *(ushort4*)(featB + (size_t)i * 4) = o;
    }
}

// ---------------- kernel 0c: Wq|Wk|Wv -> transposed bf16 [288][96] ----------------
__global__ __launch_bounds__(256) void wcvt_kernel(
    const float* __restrict__ Wq, const float* __restrict__ Wk, const float* __restrict__ Wv,
    u16* __restrict__ WcatT)
{
    int idx = blockIdx.x * 256 + threadIdx.x;
    if (idx < 288 * CC) {
        int c = idx / CC, j = idx % CC;
        float v;
        if (c < 96)       v = Wq[j * CC + c];
        else if (c < 192) v = Wk[j * CC + (c - 96)];
        else              v = Wv[j * CC + (c - 192)];
        WcatT[c * CC + j] = f2bf(v);
    }
}

// ---------------- kernel 1: fused q|k|v MFMA GEMM + epilogue ----------------
// 256 thr = 4 waves; wave = 16 rows; block = 64 rows. D[row][col]: out tile via
// mfma_f32_16x16x32_bf16: A[m=lane&15][k=quad*8+j], B[n=lane&15][k=quad*8+j],
// C/D col=lane&15, row=quad*4+reg.
#define SBS 104   // sB row stride in u16 (pad 96->104: 2-way banks = free)
__global__ __launch_bounds__(256, 2) void gemm_qkv(
    const u16* __restrict__ featB, const u16* __restrict__ WcatT,
    const float* __restrict__ bq, const float* __restrict__ gq, const float* __restrict__ betaq,
    const float* __restrict__ bk, const float* __restrict__ gk, const float* __restrict__ betak,
    const float* __restrict__ bv, const float* __restrict__ Ww1,
    u16* __restrict__ v_bf, float* __restrict__ KW1, float* __restrict__ qW1, int N)
{
    __shared__ u16 sB[288 * SBS];
    const int t = threadIdx.x;

    // stage B (27648 u16 = 3456 8-elem chunks), 16B-aligned both sides
    for (int i = t; i < 288 * 12; i += 256) {
        int row = i / 12, c8 = i % 12;
        *(float4*)(sB + row * SBS + c8 * 8) = *(const float4*)(WcatT + row * CC + c8 * 8);
    }
    __syncthreads();

    const int wave = t >> 6, lane = t & 63;
    const int m = lane & 15, quad = lane >> 4;
    const int rowbase = blockIdx.x * 64 + wave * 16;

    int arow = rowbase + m;
    if (arow >= N) arow = 0;                 // clamp; stores are guarded

    short8 a[3];
    #pragma unroll
    for (int kk = 0; kk < 3; ++kk)
        a[kk] = *(const short8*)(featB + (size_t)arow * CC + kk * 32 + quad * 8);

    f32x4 acc[18];
    #pragma unroll
    for (int nt = 0; nt < 18; ++nt) acc[nt] = (f32x4){0.f, 0.f, 0.f, 0.f};

    #pragma unroll
    for (int kk = 0; kk < 3; ++kk) {
        #pragma unroll
        for (int nt = 0; nt < 18; ++nt) {
            short8 b = *(const short8*)(sB + (nt * 16 + m) * SBS + kk * 32 + quad * 8);
            acc[nt] = __builtin_amdgcn_mfma_f32_16x16x32_bf16(a[kk], b, acc[nt], 0, 0, 0);
        }
    }

    int orow[4];
    #pragma unroll
    for (int i = 0; i < 4; ++i) orow[i] = rowbase + quad * 4 + i;
    const int cloc = m;

    // ---- v epilogue (nt 12..17) ----
    #pragma unroll
    for (int nt6 = 0; nt6 < 6; ++nt6) {
        int c = nt6 * 16 + cloc;
        float bvv = bv[c];
        #pragma unroll
        for (int i = 0; i < 4; ++i)
            if (orow[i] < N)
                v_bf[(size_t)orow[i] * CC + c] = f2bf(acc[12 + nt6][i] + bvv);
    }

    // ---- q/k epilogue: act = relu(bn(.)), reduce act@Ww1 over 16 lanes ----
    #pragma unroll
    for (int mat = 0; mat < 2; ++mat) {
        const float* bb_ = mat ? bk : bq;
        const float* gg_ = mat ? gk : gq;
        const float* be_ = mat ? betak : betaq;
        float red[4][6];
        #pragma unroll
        for (int i = 0; i < 4; ++i)
            #pragma unroll
            for (int g = 0; g < 6; ++g) red[i][g] = 0.f;

        #pragma unroll
        for (int nt6 = 0; nt6 < 6; ++nt6) {
            int nt = mat * 6 + nt6;
            int c = nt6 * 16 + cloc;
            float bb = bb_[c], sc = gg_[c] * BN_INV, be = be_[c];
            float w1r[6];
            #pragma unroll
            for (int g = 0; g < 6; ++g) w1r[g] = Ww1[c * GG + g];
            #pragma unroll
            for (int i = 0; i < 4; ++i) {
                float act = fmaxf(0.f, fmaf(acc[nt][i] + bb, sc, be));
                #pragma unroll
                for (int g = 0; g < 6; ++g)
                    red[i][g] = fmaf(act, w1r[g], red[i][g]);
            }
        }
        // butterfly over the 16 col-lanes
        #pragma unroll
        for (int st = 1; st < 16; st <<= 1)
            #pragma unroll
            for (int i = 0; i < 4; ++i)
                #pragma unroll
                for (int g = 0; g < 6; ++g)
                    red[i][g] += __shfl_xor(red[i][g], st);

        float* dst = mat ? KW1 : qW1;
        #pragma unroll
        for (int g = 0; g < 6; ++g)
            if (cloc == g)
                #pragma unroll
                for (int i = 0; i < 4; ++i)
                    if (orow[i] < N)
                        dst[(size_t)orow[i] * 8 + g] = red[i][g];
    }
}

// ---------------- kernel 2: attention, persistent waves ----------------
__global__ __launch_bounds__(256, 2) void attn_kernel(
    const float* __restrict__ coord, const int* __restrict__ ref,
    const float* __restrict__ Wp1, const float* __restrict__ bp1, const float* __restrict__ gp, const float* __restrict__ betap,
    const float* __restrict__ bp2,
    const float* __restrict__ gw, const float* __restrict__ betaw,
    const float* __restrict__ Ww2, const float* __restrict__ bw2,
    const u16* __restrict__ v_bf, const float* __restrict__ KW1, const float* __restrict__ qW1,
    const float* __restrict__ WpwT, const float* __restrict__ cvec, const float* __restrict__ Wp2,
    float* __restrict__ out, int N, int ppw)
{
    __shared__ __align__(16) float sWp2c1[32 * 100];   // Wp2 cols 64..95 transposed: [c-64][j]
    __shared__ __align__(16) float sWpw[GG * 100 + 8];
    __shared__ __align__(16) float sTail[48];          // [0..35]=Ww2, [36..41]=bw2, [42..47]=cvec
    __shared__ __align__(16) float sh[4][SS * 100];
    __shared__ __align__(16) float swt[4][SS * 8];
    __shared__ __align__(16) float sHs[4][GG * 100];
    __shared__ __align__(16) float spos[4][SS * 4];

    const int t = threadIdx.x;

    for (int i = t; i < 32 * CC; i += 256) {
        int cc = i / CC, j = i % CC;
        sWp2c1[cc * 100 + j] = Wp2[j * CC + 64 + cc];
    }
    if (t < 144) {
        int i4 = t * 4;
        int g = i4 / CC, j = i4 % CC;
        *(float4*)(sWpw + g * 100 + j) = *(const float4*)(WpwT + g * CC + j);
    }
    if (t < 36) sTail[t] = Ww2[t];
    else if (t < 42) sTail[t] = bw2[t - 36];
    else if (t < 48) sTail[t] = cvec[t - 42];
    __syncthreads();   // only block barrier; everything below is wave-private

    const int w = t >> 6, lane = t & 63;
    const int wid = blockIdx.x * 4 + w;

    float* shw  = sh[w];
    float* swtw = swt[w];
    float* sHsw = sHs[w];
    float* sposw = spos[w];

    const int c0 = lane;
    const int c1 = 64 + (lane & 31);
    const int s16 = lane & 15;
    const int g0 = lane >> 4;               // 0..3
    const int g1 = 4 + ((lane & 31) >> 4);  // 4..5

    // persistent per-lane constants
    const float w1x0 = Wp1[c0], w1y0 = Wp1[CC + c0], w1z0 = Wp1[2 * CC + c0];
    const float b10 = bp1[c0], sp0 = gp[c0] * BN_INV, bt0 = betap[c0];
    const float w1x1 = Wp1[c1], w1y1 = Wp1[CC + c1], w1z1 = Wp1[2 * CC + c1];
    const float b11 = bp1[c1], sp1 = gp[c1] * BN_INV, bt1 = betap[c1];
    const float bp2c0 = bp2[c0], bp2c1 = bp2[c1];
    float gwr[GG], bwr[GG];
    #pragma unroll
    for (int g = 0; g < GG; ++g) { gwr[g] = gw[g] * BN_INV; bwr[g] = betaw[g]; }

    // Wp2 column c0 in registers (96 VGPR); loads coalesced across lanes
    float wcol[CC];
    #pragma unroll
    for (int j = 0; j < CC; ++j) wcol[j] = Wp2[j * CC + c0];

    for (int p = 0; p < ppw; ++p) {
        const int n = wid * ppw + p;
        if (n >= N) break;

        const int idxreg = ref[n * SS + s16];

        if (lane < SS) {
            float cx = coord[n * 3 + 0];
            float cy = coord[n * 3 + 1];
            float cz = coord[n * 3 + 2];
            int j = idxreg;
            sposw[lane * 4 + 0] = coord[j * 3 + 0] - cx;
            sposw[lane * 4 + 1] = coord[j * 3 + 1] - cy;
            sposw[lane * 4 + 2] = coord[j * 3 + 2] - cz;
        }

        // ---- stage 1: h in regs + LDS ----
        float hr0[SS], hr1[SS];
        #pragma unroll
        for (int s = 0; s < SS; ++s) {
            float px = sposw[s * 4 + 0];
            float py = sposw[s * 4 + 1];
            float pz = sposw[s * 4 + 2];
            float h0 = fmaf(px, w1x0, fmaf(py, w1y0, fmaf(pz, w1z0, b10)));
            h0 = fmaxf(0.f, fmaf(h0, sp0, bt0));
            hr0[s] = h0;
            shw[s * 100 + c0] = h0;
            float h1 = fmaf(px, w1x1, fmaf(py, w1y1, fmaf(pz, w1z1, b11)));
            h1 = fmaxf(0.f, fmaf(h1, sp1, bt1));
            hr1[s] = h1;
            if (lane < 32) shw[s * 100 + c1] = h1;
        }

        // ---- stage 2: logits (4 lanes per neighbor) ----
        {
            const int qq = lane >> 4;
            const float* hrow = shw + s16 * 100 + qq * 24;
            float hg[24];
            #pragma unroll
            for (int u = 0; u < 6; ++u) {
                float4 hv = *(const float4*)(hrow + 4 * u);
                hg[4 * u + 0] = hv.x; hg[4 * u + 1] = hv.y;
                hg[4 * u + 2] = hv.z; hg[4 * u + 3] = hv.w;
            }
            float acc[GG];
            #pragma unroll
            for (int g = 0; g < GG; ++g) {
                const float* wr = sWpw + g * 100 + qq * 24;
                float a = 0.f;
                #pragma unroll
                for (int u = 0; u < 6; ++u) {
                    float4 wv = *(const float4*)(wr + 4 * u);
                    a = fmaf(hg[4 * u + 0], wv.x, fmaf(hg[4 * u + 1], wv.y,
                        fmaf(hg[4 * u + 2], wv.z, fmaf(hg[4 * u + 3], wv.w, a))));
                }
                acc[g] = a;
            }
            #pragma unroll
            for (int g = 0; g < GG; ++g) {
                acc[g] += __shfl_xor(acc[g], 16);
                acc[g] += __shfl_xor(acc[g], 32);
            }
            if (lane < SS) {
                const int jj = idxreg;
                float4 kA = *(const float4*)(KW1 + (size_t)jj * 8);
                float2 kB = *(const float2*)(KW1 + (size_t)jj * 8 + 4);
                float4 qA = *(const float4*)(qW1 + (size_t)n * 8);
                float2 qB = *(const float2*)(qW1 + (size_t)n * 8 + 4);
                float tv[GG];
                tv[0] = acc[0] + kA.x - qA.x + sTail[42];
                tv[1] = acc[1] + kA.y - qA.y + sTail[43];
                tv[2] = acc[2] + kA.z - qA.z + sTail[44];
                tv[3] = acc[3] + kA.w - qA.w + sTail[45];
                tv[4] = acc[4] + kB.x - qB.x + sTail[46];
                tv[5] = acc[5] + kB.y - qB.y + sTail[47];
                float a6[GG];
                #pragma unroll
                for (int g = 0; g < GG; ++g)
                    a6[g] = fmaxf(0.f, fmaf(tv[g], gwr[g], bwr[g]));
                #pragma unroll
                for (int gg2 = 0; gg2 < GG; ++gg2) {
                    float l = sTail[36 + gg2];
                    #pragma unroll
                    for (int g2 = 0; g2 < GG; ++g2)
                        l = fmaf(a6[g2], sTail[g2 * GG + gg2], l);
                    swtw[lane * 8 + gg2] = l;
                }
            }
        }

        // ---- stage 3: softmax over s (6 lanes) ----
        if (lane < GG) {
            const int g = lane;
            float m = -1e30f;
            #pragma unroll
            for (int s = 0; s < SS; ++s) m = fmaxf(m, swtw[s * 8 + g]);
            float e[SS];
            float sum = 0.f;
            #pragma unroll
            for (int s = 0; s < SS; ++s) { e[s] = __expf(swtw[s * 8 + g] - m); sum += e[s]; }
            float r = 1.f / sum;
            #pragma unroll
            for (int s = 0; s < SS; ++s) swtw[s * 8 + g] = e[s] * r;
        }

        // ---- stage 4: Hsum from reg h; capture per-lane weights w0s/w1s ----
        float w0s[SS], w1s[SS];
        {
            float hs0[GG] = {0.f, 0.f, 0.f, 0.f, 0.f, 0.f};
            float hs1[GG] = {0.f, 0.f, 0.f, 0.f, 0.f, 0.f};
            #pragma unroll
            for (int s = 0; s < SS; ++s) {
                float4 wa = *(const float4*)(swtw + s * 8);
                float2 wb = *(const float2*)(swtw + s * 8 + 4);
                w0s[s] = (g0 & 2) ? ((g0 & 1) ? wa.w : wa.z)
                                  : ((g0 & 1) ? wa.y : wa.x);
                w1s[s] = ((lane & 31) >> 4) ? wb.y : wb.x;
                float h0 = hr0[s], h1 = hr1[s];
                hs0[0] = fmaf(wa.x, h0, hs0[0]); hs1[0] = fmaf(wa.x, h1, hs1[0]);
                hs0[1] = fmaf(wa.y, h0, hs0[1]); hs1[1] = fmaf(wa.y, h1, hs1[1]);
                hs0[2] = fmaf(wa.z, h0, hs0[2]); hs1[2] = fmaf(wa.z, h1, hs1[2]);
                hs0[3] = fmaf(wa.w, h0, hs0[3]); hs1[3] = fmaf(wa.w, h1, hs1[3]);
                hs0[4] = fmaf(wb.x, h0, hs0[4]); hs1[4] = fmaf(wb.x, h1, hs1[4]);
                hs0[5] = fmaf(wb.y, h0, hs0[5]); hs1[5] = fmaf(wb.y, h1, hs1[5]);
            }
            #pragma unroll
            for (int g = 0; g < GG; ++g) {
                sHsw[g * 100 + c0] = hs0[g];
                if (lane < 32) sHsw[g * 100 + c1] = hs1[g];
            }
        }

        // ---- stage 5: out ----
        {
            float acc0 = bp2c0;
            float acc1 = bp2c1;
            #pragma unroll
            for (int s = 0; s < SS; ++s) {
                int jj = __shfl(idxreg, s);
                const u16* vr = v_bf + (size_t)jj * CC;
                acc0 = fmaf(us2f(vr[c0]), w0s[s], acc0);
                acc1 = fmaf(us2f(vr[c1]), w1s[s], acc1);
            }
            // c0: Hsum row g0 (bcast b128) x wcol regs
            const float* hrg0 = sHsw + g0 * 100;
            #pragma unroll
            for (int u = 0; u < 24; ++u) {
                float4 hb = *(const float4*)(hrg0 + 4 * u);
                acc0 = fmaf(hb.x, wcol[4 * u + 0], acc0);
                acc0 = fmaf(hb.y, wcol[4 * u + 1], acc0);
                acc0 = fmaf(hb.z, wcol[4 * u + 2], acc0);
                acc0 = fmaf(hb.w, wcol[4 * u + 3], acc0);
            }
            out[(size_t)n * CC + c0] = acc0;
            // c1: Hsum row g1 (bcast) x sWp2c1 row (b128)
            if (lane < 32) {
                const float* hrg1 = sHsw + g1 * 100;
                const float* wr1 = sWp2c1 + (c1 - 64) * 100;
                #pragma unroll
                for (int u = 0; u < 24; ++u) {
                    float4 hb = *(const float4*)(hrg1 + 4 * u);
                    float4 wp = *(const float4*)(wr1 + 4 * u);
                    acc1 = fmaf(hb.x, wp.x, acc1);
                    acc1 = fmaf(hb.y, wp.y, acc1);
                    acc1 = fmaf(hb.z, wp.z, acc1);
                    acc1 = fmaf(hb.w, wp.w, acc1);
                }
                out[(size_t)n * CC + c1] = acc1;
            }
        }
    }
}

extern "C" void kernel_launch(void* const* d_in, const int* in_sizes, int n_in,
                              void* d_out, int out_size, void* d_ws, size_t ws_size,
                              hipStream_t stream) {
    const float* feat  = (const float*)d_in[0];
    const float* coord = (const float*)d_in[1];
    const int*   ref   = (const int*)d_in[2];
    const float* Wq = (const float*)d_in[3],  *bq = (const float*)d_in[4],  *gq = (const float*)d_in[5],  *betaq = (const float*)d_in[6];
    const float* Wk = (const float*)d_in[7],  *bk = (const float*)d_in[8],  *gk = (const float*)d_in[9],  *betak = (const float*)d_in[10];
    const float* Wv = (const float*)d_in[11], *bv = (const float*)d_in[12];
    const float* Wp1 = (const float*)d_in[13], *bp1 = (const float*)d_in[14], *gp = (const float*)d_in[15], *betap = (const float*)d_in[16];
    const float* Wp2 = (const float*)d_in[17], *bp2 = (const float*)d_in[18];
    const float* Ww1 = (const float*)d_in[19], *bw1 = (const float*)d_in[20], *gw = (const float*)d_in[21], *betaw = (const float*)d_in[22];
    const float* Ww2 = (const float*)d_in[23], *bw2 = (const float*)d_in[24];

    const int N = in_sizes[0] / CC;   // 50000

    // workspace layout (~22.5 MB)
    float* wsf   = (float*)d_ws;
    float* KW1   = wsf;                                  // N*8 f32
    float* qW1   = KW1 + (size_t)N * 8;                  // N*8 f32
    float* WpwT  = qW1 + (size_t)N * 8;                  // 576 f32
    float* cvec  = WpwT + GG * CC;                       // 6 (pad 32)
    u16*   featB = (u16*)(cvec + 32);                    // N*96 bf16
    u16*   WcatT = featB + (size_t)N * CC;               // 288*96 bf16
    u16*   v_bf  = WcatT + 288 * CC;                     // N*96 bf16

    precompute_kernel<<<dim3(3), dim3(256), 0, stream>>>(
        Wp2, Ww1, bp2, bw1, WpwT, cvec);

    const int total4 = N * CC / 4;
    fcvt_kernel<<<dim3((total4 + 255) / 256), dim3(256), 0, stream>>>(feat, featB, total4);
    wcvt_kernel<<<dim3((288 * CC + 255) / 256), dim3(256), 0, stream>>>(Wq, Wk, Wv, WcatT);

    gemm_qkv<<<dim3((N + 63) / 64), dim3(256), 0, stream>>>(
        featB, WcatT, bq, gq, betaq, bk, gk, betak, bv, Ww1,
        v_bf, KW1, qW1, N);

    const int ppw = (N + AGRID * 4 - 1) / (AGRID * 4);   // points per wave
    attn_kernel<<<dim3(AGRID), dim3(256), 0, stream>>>(
        coord, ref, Wp1, bp1, gp, betap, bp2, gw, betaw, Ww2, bw2,
        v_bf, KW1, qW1, WpwT, cvec, Wp2, (float*)d_out, N, ppw);
}

// Round 6
// 511.230 us; speedup vs baseline: 1.0794x; 1.0794x over previous
//
#include <hip/hip_runtime.h>

typedef unsigned short u16;
typedef __attribute__((ext_vector_type(8))) short short8;   // 8 bf16 (4 VGPRs)
typedef __attribute__((ext_vector_type(4))) float f32x4;

__device__ __forceinline__ float us2f(u16 u) {
    union { unsigned int i; float f; } v; v.i = ((unsigned int)u) << 16; return v.f;
}
__device__ __forceinline__ u16 f2bf(float f) {
    unsigned int x = __float_as_uint(f);
    unsigned int r = x + 0x7fffu + ((x >> 16) & 1u);
    return (u16)(r >> 16);
}
__device__ __forceinline__ float2 bf2x(unsigned int d) {
    float2 r;
    r.x = __uint_as_float(d << 16);
    r.y = __uint_as_float(d & 0xffff0000u);
    return r;
}
__device__ __forceinline__ void bf8x(uint4 v, float* o) {
    float2 a = bf2x(v.x); o[0] = a.x; o[1] = a.y;
    float2 b = bf2x(v.y); o[2] = b.x; o[3] = b.y;
    float2 c = bf2x(v.z); o[4] = c.x; o[5] = c.y;
    float2 d = bf2x(v.w); o[6] = d.x; o[7] = d.y;
}

#define CC 96
#define SS 16
#define GG 6
#define BN_INV 0.99999500003749969f  // 1/sqrt(1+1e-5)
#define ABLK 768                     // attn blocks (3/CU), persistent
#define TOTW (ABLK * 4)

// ---------------- kernel 0: tiny precompute ----------------
__global__ __launch_bounds__(256) void precompute_kernel(
    const float* __restrict__ Wp2, const float* __restrict__ Ww1,
    const float* __restrict__ bp2, const float* __restrict__ bw1,
    float* __restrict__ WpwT, float* __restrict__ cvec)
{
    int t = blockIdx.x * 256 + threadIdx.x;
    if (t < GG * CC) {
        int g = t / CC, j = t % CC;
        float acc = 0.f;
        for (int c = 0; c < CC; ++c)
            acc = fmaf(Wp2[j * CC + c], Ww1[c * GG + g], acc);
        WpwT[g * CC + j] = acc;
    } else if (t < GG * CC + GG) {
        int g = t - GG * CC;
        float acc = bw1[g];
        for (int c = 0; c < CC; ++c)
            acc = fmaf(bp2[c], Ww1[c * GG + g], acc);
        cvec[g] = acc;
    }
}

// ---------------- kernel 0b: feat -> bf16 ----------------
__global__ __launch_bounds__(256) void fcvt_kernel(
    const float* __restrict__ feat, u16* __restrict__ featB, int total4)
{
    int i = blockIdx.x * 256 + threadIdx.x;
    if (i < total4) {
        float4 v = *(const float4*)(feat + (size_t)i * 4);
        ushort4 o;
        o.x = f2bf(v.x); o.y = f2bf(v.y); o.z = f2bf(v.z); o.w = f2bf(v.w);
        *(ushort4*)(featB + (size_t)i * 4) = o;
    }
}

// ---------------- kernel 0c: Wq|Wk|Wv -> transposed bf16 [288][96] ----------------
__global__ __launch_bounds__(256) void wcvt_kernel(
    const float* __restrict__ Wq, const float* __restrict__ Wk, const float* __restrict__ Wv,
    u16* __restrict__ WcatT)
{
    int idx = blockIdx.x * 256 + threadIdx.x;
    if (idx < 288 * CC) {
        int c = idx / CC, j = idx % CC;
        float v;
        if (c < 96)       v = Wq[j * CC + c];
        else if (c < 192) v = Wk[j * CC + (c - 96)];
        else              v = Wv[j * CC + (c - 192)];
        WcatT[c * CC + j] = f2bf(v);
    }
}

// ---------------- kernel 1: fused q|k|v MFMA GEMM + epilogue (unchanged, validated) ----------------
#define SBS 104
__global__ __launch_bounds__(256, 2) void gemm_qkv(
    const u16* __restrict__ featB, const u16* __restrict__ WcatT,
    const float* __restrict__ bq, const float* __restrict__ gq, const float* __restrict__ betaq,
    const float* __restrict__ bk, const float* __restrict__ gk, const float* __restrict__ betak,
    const float* __restrict__ bv, const float* __restrict__ Ww1,
    u16* __restrict__ v_bf, float* __restrict__ KW1, float* __restrict__ qW1, int N)
{
    __shared__ u16 sB[288 * SBS];
    const int t = threadIdx.x;

    for (int i = t; i < 288 * 12; i += 256) {
        int row = i / 12, c8 = i % 12;
        *(float4*)(sB + row * SBS + c8 * 8) = *(const float4*)(WcatT + row * CC + c8 * 8);
    }
    __syncthreads();

    const int wave = t >> 6, lane = t & 63;
    const int m = lane & 15, quad = lane >> 4;
    const int rowbase = blockIdx.x * 64 + wave * 16;

    int arow = rowbase + m;
    if (arow >= N) arow = 0;

    short8 a[3];
    #pragma unroll
    for (int kk = 0; kk < 3; ++kk)
        a[kk] = *(const short8*)(featB + (size_t)arow * CC + kk * 32 + quad * 8);

    f32x4 acc[18];
    #pragma unroll
    for (int nt = 0; nt < 18; ++nt) acc[nt] = (f32x4){0.f, 0.f, 0.f, 0.f};

    #pragma unroll
    for (int kk = 0; kk < 3; ++kk) {
        #pragma unroll
        for (int nt = 0; nt < 18; ++nt) {
            short8 b = *(const short8*)(sB + (nt * 16 + m) * SBS + kk * 32 + quad * 8);
            acc[nt] = __builtin_amdgcn_mfma_f32_16x16x32_bf16(a[kk], b, acc[nt], 0, 0, 0);
        }
    }

    int orow[4];
    #pragma unroll
    for (int i = 0; i < 4; ++i) orow[i] = rowbase + quad * 4 + i;
    const int cloc = m;

    #pragma unroll
    for (int nt6 = 0; nt6 < 6; ++nt6) {
        int c = nt6 * 16 + cloc;
        float bvv = bv[c];
        #pragma unroll
        for (int i = 0; i < 4; ++i)
            if (orow[i] < N)
                v_bf[(size_t)orow[i] * CC + c] = f2bf(acc[12 + nt6][i] + bvv);
    }

    #pragma unroll
    for (int mat = 0; mat < 2; ++mat) {
        const float* bb_ = mat ? bk : bq;
        const float* gg_ = mat ? gk : gq;
        const float* be_ = mat ? betak : betaq;
        float red[4][6];
        #pragma unroll
        for (int i = 0; i < 4; ++i)
            #pragma unroll
            for (int g = 0; g < 6; ++g) red[i][g] = 0.f;

        #pragma unroll
        for (int nt6 = 0; nt6 < 6; ++nt6) {
            int nt = mat * 6 + nt6;
            int c = nt6 * 16 + cloc;
            float bb = bb_[c], sc = gg_[c] * BN_INV, be = be_[c];
            float w1r[6];
            #pragma unroll
            for (int g = 0; g < 6; ++g) w1r[g] = Ww1[c * GG + g];
            #pragma unroll
            for (int i = 0; i < 4; ++i) {
                float act = fmaxf(0.f, fmaf(acc[nt][i] + bb, sc, be));
                #pragma unroll
                for (int g = 0; g < 6; ++g)
                    red[i][g] = fmaf(act, w1r[g], red[i][g]);
            }
        }
        #pragma unroll
        for (int st = 1; st < 16; st <<= 1)
            #pragma unroll
            for (int i = 0; i < 4; ++i)
                #pragma unroll
                for (int g = 0; g < 6; ++g)
                    red[i][g] += __shfl_xor(red[i][g], st);

        float* dst = mat ? KW1 : qW1;
        #pragma unroll
        for (int g = 0; g < 6; ++g)
            if (cloc == g)
                #pragma unroll
                for (int i = 0; i < 4; ++i)
                    if (orow[i] < N)
                        dst[(size_t)orow[i] * 8 + g] = red[i][g];
    }
}

// ---------------- kernel 2: attention v3 ----------------
// Persistent, 4 waves/block, 1 pt/wave/iter, pair-channel mapping (lane L<48
// owns channels 2L,2L+1, both in group L>>3). v-gather prefetched at loop top
// as 16 coalesced dword loads. No in-loop barriers (wave-private LDS).
__global__ __launch_bounds__(256) void attn_kernel(
    const float* __restrict__ coord, const int* __restrict__ ref,
    const float* __restrict__ Wp1, const float* __restrict__ bp1, const float* __restrict__ gp, const float* __restrict__ betap,
    const float* __restrict__ bp2,
    const float* __restrict__ gw, const float* __restrict__ betaw,
    const float* __restrict__ Ww2, const float* __restrict__ bw2,
    const u16* __restrict__ v_bf, const float* __restrict__ KW1, const float* __restrict__ qW1,
    const float* __restrict__ WpwT, const float* __restrict__ cvec, const float* __restrict__ Wp2,
    float* __restrict__ out, int N)
{
    __shared__ __align__(16) u16   sWp2T[CC * 104];    // [c][j] bf16, stride 104
    __shared__ __align__(16) u16   sWpw[GG * 104];     // [g][j] bf16
    __shared__ __align__(16) u16   shh[4][SS * 104];   // h bf16, [s][c] pairs, per wave
    __shared__ __align__(16) float swt[4][SS * 8];     // softmax weights per wave
    __shared__ __align__(16) float sHs[4][GG * 100];   // Hsum fp32 per wave

    const int t = threadIdx.x;
    for (int i = t; i < CC * CC; i += 256) {
        int c = i % CC, j = i / CC;                    // consecutive t -> consecutive c (coalesced read)
        sWp2T[c * 104 + j] = f2bf(Wp2[j * CC + c]);
    }
    for (int i = t; i < GG * CC; i += 256) {
        int g = i / CC, j = i % CC;
        sWpw[g * 104 + j] = f2bf(WpwT[g * CC + j]);
    }
    __syncthreads();   // only barrier; all below is wave-private

    const int w = t >> 6, lane = t & 63;
    const int wid = blockIdx.x * 4 + w;
    u16*   shw  = shh[w];
    float* swtw = swt[w];
    float* sHsw = sHs[w];

    const int  L   = (lane < 48) ? lane : 47;          // clamp; writes guarded by act
    const bool act = lane < 48;
    const int  cA = 2 * L, cB = 2 * L + 1;
    const int  gL = L >> 3;
    const int  s16 = lane & 15, qq = lane >> 4;

    // hoisted per-lane constants
    const float w1xA = Wp1[cA], w1yA = Wp1[CC + cA], w1zA = Wp1[2 * CC + cA];
    const float w1xB = Wp1[cB], w1yB = Wp1[CC + cB], w1zB = Wp1[2 * CC + cB];
    const float b1A = bp1[cA], spA = gp[cA] * BN_INV, btA = betap[cA];
    const float b1B = bp1[cB], spB = gp[cB] * BN_INV, btB = betap[cB];
    const float bpA = bp2[cA], bpB = bp2[cB];

    for (int n = wid; n < N; n += TOTW) {
        // ---- prefetch: everything address-dependent issues here ----
        const int idxreg = ref[n * SS + s16];

        float px = 0.f, py = 0.f, pz = 0.f;
        float4 kAv = {0,0,0,0}; float2 kBv = {0,0};
        float4 qAv = {0,0,0,0}; float2 qBv = {0,0};
        if (lane < SS) {
            int j = idxreg;
            px = coord[j * 3 + 0] - coord[n * 3 + 0];
            py = coord[j * 3 + 1] - coord[n * 3 + 1];
            pz = coord[j * 3 + 2] - coord[n * 3 + 2];
            const float* kr = KW1 + (size_t)idxreg * 8;
            kAv = *(const float4*)kr; kBv = *(const float2*)(kr + 4);
            const float* qr = qW1 + (size_t)n * 8;
            qAv = *(const float4*)qr; qBv = *(const float2*)(qr + 4);
        }

        unsigned int vpre[SS];    // v[j_s][cA..cB] packed bf16 pair
        #pragma unroll
        for (int s = 0; s < SS; ++s) {
            int jj = __shfl(idxreg, s);
            vpre[s] = *(const unsigned int*)(v_bf + (size_t)jj * CC + cA);
        }

        // ---- stage 1: h = relu(bn(pos@Wp1)), bf16 pairs to LDS ----
        #pragma unroll
        for (int s = 0; s < SS; ++s) {
            float pxs = __shfl(px, s), pys = __shfl(py, s), pzs = __shfl(pz, s);
            float hA = fmaf(pxs, w1xA, fmaf(pys, w1yA, fmaf(pzs, w1zA, b1A)));
            hA = fmaxf(0.f, fmaf(hA, spA, btA));
            float hB = fmaf(pxs, w1xB, fmaf(pys, w1yB, fmaf(pzs, w1zB, b1B)));
            hB = fmaxf(0.f, fmaf(hB, spB, btB));
            if (act) {
                unsigned int d = ((unsigned int)f2bf(hB) << 16) | (unsigned int)f2bf(hA);
                *(unsigned int*)(shw + s * 104 + cA) = d;
            }
        }

        // ---- stage 2: logits; 4 lanes per neighbor, 24-channel slices ----
        {
            float hg[24];
            const u16* hrow = shw + s16 * 104 + qq * 24;
            uint4 h0 = *(const uint4*)(hrow);
            uint4 h1 = *(const uint4*)(hrow + 8);
            uint4 h2 = *(const uint4*)(hrow + 16);
            bf8x(h0, hg); bf8x(h1, hg + 8); bf8x(h2, hg + 16);

            float acc[GG];
            #pragma unroll
            for (int g = 0; g < GG; ++g) {
                const u16* wr = sWpw + g * 104 + qq * 24;
                uint4 w0 = *(const uint4*)(wr);
                uint4 w1 = *(const uint4*)(wr + 8);
                uint4 w2 = *(const uint4*)(wr + 16);
                float wg[24];
                bf8x(w0, wg); bf8x(w1, wg + 8); bf8x(w2, wg + 16);
                float a = 0.f;
                #pragma unroll
                for (int u = 0; u < 24; ++u)
                    a = fmaf(hg[u], wg[u], a);
                acc[g] = a;
            }
            #pragma unroll
            for (int g = 0; g < GG; ++g) {
                acc[g] += __shfl_xor(acc[g], 16);
                acc[g] += __shfl_xor(acc[g], 32);
            }

            if (lane < SS) {
                float tv[GG];
                tv[0] = acc[0] + kAv.x - qAv.x + cvec[0];
                tv[1] = acc[1] + kAv.y - qAv.y + cvec[1];
                tv[2] = acc[2] + kAv.z - qAv.z + cvec[2];
                tv[3] = acc[3] + kAv.w - qAv.w + cvec[3];
                tv[4] = acc[4] + kBv.x - qBv.x + cvec[4];
                tv[5] = acc[5] + kBv.y - qBv.y + cvec[5];
                float a6[GG];
                #pragma unroll
                for (int g = 0; g < GG; ++g)
                    a6[g] = fmaxf(0.f, fmaf(tv[g], gw[g] * BN_INV, betaw[g]));
                float l[GG];
                #pragma unroll
                for (int gg2 = 0; gg2 < GG; ++gg2) {
                    float lv = bw2[gg2];
                    #pragma unroll
                    for (int g2 = 0; g2 < GG; ++g2)
                        lv = fmaf(a6[g2], Ww2[g2 * GG + gg2], lv);
                    l[gg2] = lv;
                }
                // softmax over the 16 neighbor-lanes via butterfly
                float wgt[GG];
                #pragma unroll
                for (int g = 0; g < GG; ++g) {
                    float m = l[g];
                    m = fmaxf(m, __shfl_xor(m, 1));
                    m = fmaxf(m, __shfl_xor(m, 2));
                    m = fmaxf(m, __shfl_xor(m, 4));
                    m = fmaxf(m, __shfl_xor(m, 8));
                    float e = __expf(l[g] - m);
                    float ssum = e;
                    ssum += __shfl_xor(ssum, 1);
                    ssum += __shfl_xor(ssum, 2);
                    ssum += __shfl_xor(ssum, 4);
                    ssum += __shfl_xor(ssum, 8);
                    wgt[g] = e / ssum;
                }
                *(float2*)(swtw + s16 * 8 + 0) = make_float2(wgt[0], wgt[1]);
                *(float2*)(swtw + s16 * 8 + 2) = make_float2(wgt[2], wgt[3]);
                *(float2*)(swtw + s16 * 8 + 4) = make_float2(wgt[4], wgt[5]);
            }
        }

        // ---- stage 4: Hsum (all 6 g, 2 channels) + capture w[s][gL] ----
        float wreg[SS];
        {
            float hsA[GG] = {0.f, 0.f, 0.f, 0.f, 0.f, 0.f};
            float hsB[GG] = {0.f, 0.f, 0.f, 0.f, 0.f, 0.f};
            #pragma unroll
            for (int s = 0; s < SS; ++s) {
                unsigned int hd = *(const unsigned int*)(shw + s * 104 + cA);
                float2 h2 = bf2x(hd);
                float4 wa = *(const float4*)(swtw + s * 8);       // broadcast
                float2 wb = *(const float2*)(swtw + s * 8 + 4);
                wreg[s] = (gL < 4) ? ((gL & 2) ? ((gL & 1) ? wa.w : wa.z)
                                               : ((gL & 1) ? wa.y : wa.x))
                                   : ((gL & 1) ? wb.y : wb.x);
                hsA[0] = fmaf(wa.x, h2.x, hsA[0]); hsB[0] = fmaf(wa.x, h2.y, hsB[0]);
                hsA[1] = fmaf(wa.y, h2.x, hsA[1]); hsB[1] = fmaf(wa.y, h2.y, hsB[1]);
                hsA[2] = fmaf(wa.z, h2.x, hsA[2]); hsB[2] = fmaf(wa.z, h2.y, hsB[2]);
                hsA[3] = fmaf(wa.w, h2.x, hsA[3]); hsB[3] = fmaf(wa.w, h2.y, hsB[3]);
                hsA[4] = fmaf(wb.x, h2.x, hsA[4]); hsB[4] = fmaf(wb.x, h2.y, hsB[4]);
                hsA[5] = fmaf(wb.y, h2.x, hsA[5]); hsB[5] = fmaf(wb.y, h2.y, hsB[5]);
            }
            if (act) {
                #pragma unroll
                for (int g = 0; g < GG; ++g)
                    *(float2*)(sHsw + g * 100 + cA) = make_float2(hsA[g], hsB[g]);
            }
        }

        // ---- stage 5: out = v-part + Hsum[gL]@Wp2T rows + bp2 ----
        {
            float accA = bpA, accB = bpB;
            #pragma unroll
            for (int s = 0; s < SS; ++s) {
                float2 v2 = bf2x(vpre[s]);
                accA = fmaf(v2.x, wreg[s], accA);
                accB = fmaf(v2.y, wreg[s], accB);
            }
            const float* hrg = sHsw + gL * 100;
            const u16* wrA = sWp2T + cA * 104;
            const u16* wrB = sWp2T + cB * 104;
            #pragma unroll
            for (int u = 0; u < 12; ++u) {
                float4 hb0 = *(const float4*)(hrg + 8 * u);
                float4 hb1 = *(const float4*)(hrg + 8 * u + 4);
                float wa[8], wb[8];
                bf8x(*(const uint4*)(wrA + 8 * u), wa);
                bf8x(*(const uint4*)(wrB + 8 * u), wb);
                accA = fmaf(hb0.x, wa[0], accA); accB = fmaf(hb0.x, wb[0], accB);
                accA = fmaf(hb0.y, wa[1], accA); accB = fmaf(hb0.y, wb[1], accB);
                accA = fmaf(hb0.z, wa[2], accA); accB = fmaf(hb0.z, wb[2], accB);
                accA = fmaf(hb0.w, wa[3], accA); accB = fmaf(hb0.w, wb[3], accB);
                accA = fmaf(hb1.x, wa[4], accA); accB = fmaf(hb1.x, wb[4], accB);
                accA = fmaf(hb1.y, wa[5], accA); accB = fmaf(hb1.y, wb[5], accB);
                accA = fmaf(hb1.z, wa[6], accA); accB = fmaf(hb1.z, wb[6], accB);
                accA = fmaf(hb1.w, wa[7], accA); accB = fmaf(hb1.w, wb[7], accB);
            }
            if (act)
                *(float2*)(out + (size_t)n * CC + cA) = make_float2(accA, accB);
        }
    }
}

extern "C" void kernel_launch(void* const* d_in, const int* in_sizes, int n_in,
                              void* d_out, int out_size, void* d_ws, size_t ws_size,
                              hipStream_t stream) {
    const float* feat  = (const float*)d_in[0];
    const float* coord = (const float*)d_in[1];
    const int*   ref   = (const int*)d_in[2];
    const float* Wq = (const float*)d_in[3],  *bq = (const float*)d_in[4],  *gq = (const float*)d_in[5],  *betaq = (const float*)d_in[6];
    const float* Wk = (const float*)d_in[7],  *bk = (const float*)d_in[8],  *gk = (const float*)d_in[9],  *betak = (const float*)d_in[10];
    const float* Wv = (const float*)d_in[11], *bv = (const float*)d_in[12];
    const float* Wp1 = (const float*)d_in[13], *bp1 = (const float*)d_in[14], *gp = (const float*)d_in[15], *betap = (const float*)d_in[16];
    const float* Wp2 = (const float*)d_in[17], *bp2 = (const float*)d_in[18];
    const float* Ww1 = (const float*)d_in[19], *bw1 = (const float*)d_in[20], *gw = (const float*)d_in[21], *betaw = (const float*)d_in[22];
    const float* Ww2 = (const float*)d_in[23], *bw2 = (const float*)d_in[24];

    const int N = in_sizes[0] / CC;   // 50000

    // workspace layout (~22.5 MB)
    float* wsf   = (float*)d_ws;
    float* KW1   = wsf;                                  // N*8 f32
    float* qW1   = KW1 + (size_t)N * 8;                  // N*8 f32
    float* WpwT  = qW1 + (size_t)N * 8;                  // 576 f32
    float* cvec  = WpwT + GG * CC;                       // 6 (pad 32)
    u16*   featB = (u16*)(cvec + 32);                    // N*96 bf16
    u16*   WcatT = featB + (size_t)N * CC;               // 288*96 bf16
    u16*   v_bf  = WcatT + 288 * CC;                     // N*96 bf16

    precompute_kernel<<<dim3(3), dim3(256), 0, stream>>>(
        Wp2, Ww1, bp2, bw1, WpwT, cvec);

    const int total4 = N * CC / 4;
    fcvt_kernel<<<dim3((total4 + 255) / 256), dim3(256), 0, stream>>>(feat, featB, total4);
    wcvt_kernel<<<dim3((288 * CC + 255) / 256), dim3(256), 0, stream>>>(Wq, Wk, Wv, WcatT);

    gemm_qkv<<<dim3((N + 63) / 64), dim3(256), 0, stream>>>(
        featB, WcatT, bq, gq, betaq, bk, gk, betak, bv, Ww1,
        v_bf, KW1, qW1, N);

    attn_kernel<<<dim3(ABLK), dim3(256), 0, stream>>>(
        coord, ref, Wp1, bp1, gp, betap, bp2, gw, betaw, Ww2, bw2,
        v_bf, KW1, qW1, WpwT, cvec, Wp2, (float*)d_out, N);
}